// Round 1
// baseline (275.853 us; speedup 1.0000x reference)
//
#include <hip/hip_runtime.h>

typedef unsigned short u16;
typedef __attribute__((ext_vector_type(8))) short short8;   // 8 x bf16 (4 VGPRs)
typedef __attribute__((ext_vector_type(4))) float f32x4;    // MFMA accumulator

__device__ __forceinline__ u16 f2bf(float f){
  union { float f; unsigned u; } v; v.f = f;
  unsigned u = v.u;
  u += 0x7fffu + ((u >> 16) & 1u);   // RNE
  return (u16)(u >> 16);
}

// ---------------------------------------------------------------------------
// Kernel 1: fused theta/phi/g projections.
// out[b][co][hw] = sum_k w[co][k] * x[b][k][hw] + bias[co], written as bf16.
// Tile: 64 co x 64 hw per block, micro 4x4 per thread, K-chunks of 16.
// grid: (16 hw-tiles, 3 proj * 2 co-tiles, 8 b)
// ---------------------------------------------------------------------------
__global__ __launch_bounds__(256) void proj3_kernel(
    const float* __restrict__ x,
    const float* __restrict__ tw, const float* __restrict__ tb,
    const float* __restrict__ pw, const float* __restrict__ pb,
    const float* __restrict__ gw, const float* __restrict__ gb,
    u16* __restrict__ T, u16* __restrict__ PHI, u16* __restrict__ G)
{
  const int proj = blockIdx.y >> 1;
  const int co0  = (blockIdx.y & 1) * 64;
  const float* __restrict__ W    = (proj==0) ? tw : ((proj==1) ? pw : gw);
  const float* __restrict__ bias = (proj==0) ? tb : ((proj==1) ? pb : gb);
  u16* __restrict__ out          = (proj==0) ? T  : ((proj==1) ? PHI : G);
  const int b   = blockIdx.z;
  const int hw0 = blockIdx.x * 64;
  const float* srcb = x + (size_t)b * 262144;   // 256*1024

  __shared__ float xs[16][64];
  __shared__ float wT[16][64];
  const int t = threadIdx.x;
  const int tc = t >> 4, th = t & 15;

  float acc[4][4];
  #pragma unroll
  for (int i=0;i<4;i++)
    #pragma unroll
    for (int j=0;j<4;j++) acc[i][j] = 0.f;

  for (int k0 = 0; k0 < 256; k0 += 16){
    __syncthreads();
    {
      int kk = t >> 4, col = (t & 15) * 4;
      *(float4*)&xs[kk][col] = *(const float4*)&srcb[(size_t)(k0+kk)*1024 + hw0 + col];
    }
    {
      int c = t >> 2, kk0 = (t & 3) * 4;
      float4 w4 = *(const float4*)&W[(size_t)(co0 + c) * 256 + k0 + kk0];
      wT[kk0+0][c] = w4.x; wT[kk0+1][c] = w4.y;
      wT[kk0+2][c] = w4.z; wT[kk0+3][c] = w4.w;
    }
    __syncthreads();
    #pragma unroll
    for (int kk=0;kk<16;kk++){
      float4 bv = *(const float4*)&xs[kk][th*4];
      float4 av = *(const float4*)&wT[kk][tc*4];
      float a[4]  = {av.x, av.y, av.z, av.w};
      float bb[4] = {bv.x, bv.y, bv.z, bv.w};
      #pragma unroll
      for (int i=0;i<4;i++)
        #pragma unroll
        for (int j=0;j<4;j++)
          acc[i][j] += a[i]*bb[j];
    }
  }
  #pragma unroll
  for (int i=0;i<4;i++){
    int co = co0 + tc*4 + i;
    float bs = bias[co];
    size_t base = ((size_t)b*128 + co)*1024 + hw0 + th*4;
    ushort4 u;
    u.x = f2bf(acc[i][0]+bs); u.y = f2bf(acc[i][1]+bs);
    u.z = f2bf(acc[i][2]+bs); u.w = f2bf(acc[i][3]+bs);
    *(ushort4*)&out[base] = u;
  }
}

// ---------------------------------------------------------------------------
// Kernel 2: bf16 2D transpose, dst[c][r] = src[r][c].  64x64 tiles.
// Used for:  phi [128][8192] -> K [8192][128]   (grid 128,2)
//            g   [8192][128] -> VT [128][8192]  (grid 2,128)
// ---------------------------------------------------------------------------
__global__ __launch_bounds__(256) void transpose_bf_kernel(
    const u16* __restrict__ src, u16* __restrict__ dst, int R, int C)
{
  __shared__ u16 tile[64][72];
  const int t = threadIdx.x;
  const int c0 = blockIdx.x*64, r0 = blockIdx.y*64;
  {
    int rr = t >> 2, cs = (t & 3) * 16;
    const u16* s = src + (size_t)(r0+rr)*C + c0 + cs;
    uint4 a0 = *(const uint4*)s;
    uint4 a1 = *(const uint4*)(s+8);
    *(uint4*)&tile[rr][cs]   = a0;
    *(uint4*)&tile[rr][cs+8] = a1;
  }
  __syncthreads();
  {
    int cc = t >> 2, rs = (t & 3) * 16;
    __align__(16) u16 tmp[16];
    #pragma unroll
    for (int i=0;i<16;i++) tmp[i] = tile[rs+i][cc];
    u16* d = dst + (size_t)(c0+cc)*R + r0 + rs;
    *(uint4*)d     = *(uint4*)&tmp[0];
    *(uint4*)(d+8) = *(uint4*)&tmp[8];
  }
}

// ---------------------------------------------------------------------------
// Kernel 3: flash attention, no-max-subtraction online softmax.
// Q=T [8192][128], K [8192][128], VT [128][8192], all bf16. O fp32 [8192][128].
// Block: 32 queries, 4 waves; each wave owns a 32-key slice of each
// 128-key tile; unnormalized (O~, l) summed across waves at the end.
// ---------------------------------------------------------------------------
__global__ __launch_bounds__(256) void attn_kernel(
    const u16* __restrict__ Tq, const u16* __restrict__ Kk,
    const u16* __restrict__ Vt, float* __restrict__ O)
{
  __shared__ __align__(16) char smem[47104];
  u16* Ks = (u16*)smem;                  // [128][136] bf16, +8 pad (bank/align)
  u16* Ps = (u16*)(smem + 34816);        // 4 x [32][48] bf16
  const int t = threadIdx.x;
  const int wave = t >> 6, lane = t & 63;
  const int quad = lane >> 4, n16 = lane & 15;
  const int q0 = blockIdx.x * 32;
  u16* Pw = Ps + wave * 1536;
  const int kb = wave * 32;              // this wave's key slice in the tile

  // Q fragments: A[m=lane&15][k=quad*8+j]
  short8 qa[2][4];
  #pragma unroll
  for (int mt=0;mt<2;mt++)
    #pragma unroll
    for (int kc=0;kc<4;kc++)
      qa[mt][kc] = *(const short8*)(Tq + (size_t)(q0 + mt*16 + n16)*128 + kc*32 + quad*8);

  f32x4 o[2][8];
  float lp[2][4];
  #pragma unroll
  for (int mt=0;mt<2;mt++){
    #pragma unroll
    for (int dt=0;dt<8;dt++){ f32x4 z = {0.f,0.f,0.f,0.f}; o[mt][dt] = z; }
    #pragma unroll
    for (int r=0;r<4;r++) lp[mt][r] = 0.f;
  }

  for (int kt=0;kt<64;kt++){
    const int key0 = kt*128;
    __syncthreads();
    // stage K tile [128 keys][128 d] -> LDS (b64 writes, ~4-way worst)
    #pragma unroll
    for (int p=0;p<16;p++){
      int r = p*8 + (t>>5);
      int c = (t&31)*4;
      *(uint2*)(Ks + r*136 + c) = *(const uint2*)(Kk + (size_t)(key0 + r)*128 + c);
    }
    // V fragments straight from global VT (B[n=d][k=key]); issued early so
    // QK+softmax hides their latency.  Each element read exactly once/block.
    short8 vf[8];
    #pragma unroll
    for (int dt=0;dt<8;dt++)
      vf[dt] = *(const short8*)(Vt + (size_t)(dt*16 + n16)*8192 + key0 + kb + quad*8);
    __syncthreads();

    // K fragments: B[n=key][k=d]
    short8 kf[2][4];
    #pragma unroll
    for (int nt=0;nt<2;nt++)
      #pragma unroll
      for (int kc=0;kc<4;kc++)
        kf[nt][kc] = *(const short8*)(Ks + (kb + nt*16 + n16)*136 + kc*32 + quad*8);

    // S = Q K^T for this wave's 32x32 block
    f32x4 s[2][2];
    #pragma unroll
    for (int mt=0;mt<2;mt++)
      #pragma unroll
      for (int nt=0;nt<2;nt++){
        f32x4 a = {0.f,0.f,0.f,0.f};
        #pragma unroll
        for (int kc=0;kc<4;kc++)
          a = __builtin_amdgcn_mfma_f32_16x16x32_bf16(qa[mt][kc], kf[nt][kc], a, 0, 0, 0);
        s[mt][nt] = a;
      }

    // P = exp(S) (no max subtraction: |S| <= ~43, safe in fp32), l partials,
    // and C-layout -> LDS [q][key] for the A-operand of PV.
    #pragma unroll
    for (int mt=0;mt<2;mt++)
      #pragma unroll
      for (int nt=0;nt<2;nt++)
        #pragma unroll
        for (int r=0;r<4;r++){
          float pe = exp2f(s[mt][nt][r] * 1.4426950408889634f);
          lp[mt][r] += pe;
          Pw[(mt*16 + quad*4 + r)*48 + nt*16 + n16] = f2bf(pe);
        }

    // P fragments: A[m=lane&15][k=quad*8+j]
    short8 pf[2];
    #pragma unroll
    for (int mt=0;mt<2;mt++)
      pf[mt] = *(const short8*)(Pw + (mt*16 + n16)*48 + quad*8);

    // O~ += P V
    #pragma unroll
    for (int dt=0;dt<8;dt++)
      #pragma unroll
      for (int mt=0;mt<2;mt++)
        o[mt][dt] = __builtin_amdgcn_mfma_f32_16x16x32_bf16(pf[mt], vf[dt], o[mt][dt], 0, 0, 0);
  }

  // row-sum l across the 16-lane column groups
  float l[2][4];
  #pragma unroll
  for (int mt=0;mt<2;mt++)
    #pragma unroll
    for (int r=0;r<4;r++){
      float v = lp[mt][r];
      v += __shfl_xor(v, 1, 64);
      v += __shfl_xor(v, 2, 64);
      v += __shfl_xor(v, 4, 64);
      v += __shfl_xor(v, 8, 64);
      l[mt][r] = v;
    }

  // cross-wave merge (plain sums; overlay Ks/Ps LDS)
  __syncthreads();
  float* Om = (float*)smem;             // [2][32][128] fp32 (32 KB)
  float* lm = (float*)(smem + 40960);   // 64 floats
  if (wave >= 2){
    const int w2 = wave - 2;
    #pragma unroll
    for (int mt=0;mt<2;mt++){
      #pragma unroll
      for (int dt=0;dt<8;dt++)
        #pragma unroll
        for (int r=0;r<4;r++)
          Om[(w2*32 + mt*16 + quad*4 + r)*128 + dt*16 + n16] = o[mt][dt][r];
      if (n16 == 0)
        #pragma unroll
        for (int r=0;r<4;r++) lm[w2*32 + mt*16 + quad*4 + r] = l[mt][r];
    }
  }
  __syncthreads();
  if (wave < 2){
    #pragma unroll
    for (int mt=0;mt<2;mt++){
      #pragma unroll
      for (int dt=0;dt<8;dt++)
        #pragma unroll
        for (int r=0;r<4;r++)
          o[mt][dt][r] += Om[(wave*32 + mt*16 + quad*4 + r)*128 + dt*16 + n16];
      #pragma unroll
      for (int r=0;r<4;r++) l[mt][r] += lm[wave*32 + mt*16 + quad*4 + r];
    }
  }
  __syncthreads();
  if (wave == 1){
    #pragma unroll
    for (int mt=0;mt<2;mt++){
      #pragma unroll
      for (int dt=0;dt<8;dt++)
        #pragma unroll
        for (int r=0;r<4;r++)
          Om[(mt*16 + quad*4 + r)*128 + dt*16 + n16] = o[mt][dt][r];
      if (n16 == 0)
        #pragma unroll
        for (int r=0;r<4;r++) lm[mt*16 + quad*4 + r] = l[mt][r];
    }
  }
  __syncthreads();
  if (wave == 0){
    #pragma unroll
    for (int mt=0;mt<2;mt++){
      #pragma unroll
      for (int dt=0;dt<8;dt++)
        #pragma unroll
        for (int r=0;r<4;r++)
          o[mt][dt][r] += Om[(mt*16 + quad*4 + r)*128 + dt*16 + n16];
      #pragma unroll
      for (int r=0;r<4;r++) l[mt][r] += lm[mt*16 + quad*4 + r];
    }
    #pragma unroll
    for (int mt=0;mt<2;mt++){
      float inv[4];
      #pragma unroll
      for (int r=0;r<4;r++) inv[r] = 1.0f / l[mt][r];
      #pragma unroll
      for (int dt=0;dt<8;dt++)
        #pragma unroll
        for (int r=0;r<4;r++)
          O[(size_t)(q0 + mt*16 + quad*4 + r)*128 + dt*16 + n16] = o[mt][dt][r] * inv[r];
    }
  }
}

// ---------------------------------------------------------------------------
// Kernel 4: final 1x1 conv + bias + residual (fp32).
// out[b][co][hw] = sum_j Ww[co][j]*O[b][j][hw] + Wb[co] + x[b][co][hw]
// grid: (16 hw-tiles, 4 co-tiles, 8 b)
// ---------------------------------------------------------------------------
__global__ __launch_bounds__(256) void final_kernel(
    const float* __restrict__ Ww, const float* __restrict__ Wb,
    const float* __restrict__ Osrc, const float* __restrict__ x,
    float* __restrict__ outp)
{
  const int b   = blockIdx.z;
  const int co0 = blockIdx.y * 64;
  const int hw0 = blockIdx.x * 64;
  const float* srcb = Osrc + (size_t)b * 131072;   // 128*1024

  __shared__ float xs[16][64];
  __shared__ float wT[16][64];
  const int t = threadIdx.x;
  const int tc = t >> 4, th = t & 15;

  float acc[4][4];
  #pragma unroll
  for (int i=0;i<4;i++)
    #pragma unroll
    for (int j=0;j<4;j++) acc[i][j] = 0.f;

  for (int k0 = 0; k0 < 128; k0 += 16){
    __syncthreads();
    {
      int kk = t >> 4, col = (t & 15) * 4;
      *(float4*)&xs[kk][col] = *(const float4*)&srcb[(size_t)(k0+kk)*1024 + hw0 + col];
    }
    {
      int c = t >> 2, kk0 = (t & 3) * 4;
      float4 w4 = *(const float4*)&Ww[(size_t)(co0 + c) * 128 + k0 + kk0];
      wT[kk0+0][c] = w4.x; wT[kk0+1][c] = w4.y;
      wT[kk0+2][c] = w4.z; wT[kk0+3][c] = w4.w;
    }
    __syncthreads();
    #pragma unroll
    for (int kk=0;kk<16;kk++){
      float4 bv = *(const float4*)&xs[kk][th*4];
      float4 av = *(const float4*)&wT[kk][tc*4];
      float a[4]  = {av.x, av.y, av.z, av.w};
      float bb[4] = {bv.x, bv.y, bv.z, bv.w};
      #pragma unroll
      for (int i=0;i<4;i++)
        #pragma unroll
        for (int j=0;j<4;j++)
          acc[i][j] += a[i]*bb[j];
    }
  }
  #pragma unroll
  for (int i=0;i<4;i++){
    int co = co0 + tc*4 + i;
    float bs = Wb[co];
    size_t base = ((size_t)b*256 + co)*1024 + hw0 + th*4;
    float4 xr = *(const float4*)&x[base];
    float4 r;
    r.x = acc[i][0] + bs + xr.x;
    r.y = acc[i][1] + bs + xr.y;
    r.z = acc[i][2] + bs + xr.z;
    r.w = acc[i][3] + bs + xr.w;
    *(float4*)&outp[base] = r;
  }
}

// ---------------------------------------------------------------------------
extern "C" void kernel_launch(void* const* d_in, const int* in_sizes, int n_in,
                              void* d_out, int out_size, void* d_ws, size_t ws_size,
                              hipStream_t stream)
{
  (void)in_sizes; (void)n_in; (void)out_size; (void)ws_size;
  const float* x  = (const float*)d_in[0];
  const float* tw = (const float*)d_in[1];
  const float* tb = (const float*)d_in[2];
  const float* pw = (const float*)d_in[3];
  const float* pb = (const float*)d_in[4];
  const float* gw = (const float*)d_in[5];
  const float* gb = (const float*)d_in[6];
  const float* Ww = (const float*)d_in[7];
  const float* Wb = (const float*)d_in[8];
  float* outp = (float*)d_out;

  char* ws = (char*)d_ws;
  const size_t MB = 1u << 20;
  u16*   Tbf   = (u16*)(ws);            // 2 MB  theta bf16 [8192][128]
  u16*   PHIbf = (u16*)(ws + 2*MB);     // 2 MB  phi   bf16 [128][8192] (natural flat)
  u16*   Gbf   = (u16*)(ws + 4*MB);     // 2 MB  g     bf16 [8192][128]
  u16*   Kbf   = (u16*)(ws + 6*MB);     // 2 MB  K = phi^T  [8192][128]
  u16*   VTbf  = (u16*)(ws + 8*MB);     // 2 MB  VT = g^T   [128][8192]
  float* Obuf  = (float*)(ws + 2*MB);   // 4 MB  O fp32, overlays dead PHI+G

  proj3_kernel<<<dim3(16, 6, 8), 256, 0, stream>>>(x, tw, tb, pw, pb, gw, gb,
                                                   Tbf, PHIbf, Gbf);
  transpose_bf_kernel<<<dim3(128, 2), 256, 0, stream>>>(PHIbf, Kbf, 128, 8192);
  transpose_bf_kernel<<<dim3(2, 128), 256, 0, stream>>>(Gbf, VTbf, 8192, 128);
  attn_kernel<<<dim3(256), 256, 0, stream>>>(Tbf, Kbf, VTbf, Obuf);
  final_kernel<<<dim3(16, 4, 8), 256, 0, stream>>>(Ww, Wb, Obuf, x, outp);
}

// Round 2
// 221.730 us; speedup vs baseline: 1.2441x; 1.2441x over previous
//
#include <hip/hip_runtime.h>

typedef unsigned short u16;
typedef __attribute__((ext_vector_type(8))) short short8;   // 8 x bf16 (4 VGPRs)
typedef __attribute__((ext_vector_type(4))) float f32x4;    // MFMA accumulator

__device__ __forceinline__ u16 f2bf(float f){
  union { float f; unsigned u; } v; v.f = f;
  unsigned u = v.u;
  u += 0x7fffu + ((u >> 16) & 1u);   // RNE
  return (u16)(u >> 16);
}

// ---------------------------------------------------------------------------
// Kernel 1: fused theta/phi/g projections.
// out[b][co][hw] = sum_k w[co][k] * x[b][k][hw] + bias[co], written as bf16.
// Tile: 64 co x 64 hw per block, micro 4x4 per thread, K-chunks of 16.
// grid: (16 hw-tiles, 3 proj * 2 co-tiles, 8 b)
// ---------------------------------------------------------------------------
__global__ __launch_bounds__(256) void proj3_kernel(
    const float* __restrict__ x,
    const float* __restrict__ tw, const float* __restrict__ tb,
    const float* __restrict__ pw, const float* __restrict__ pb,
    const float* __restrict__ gw, const float* __restrict__ gb,
    u16* __restrict__ T, u16* __restrict__ PHI, u16* __restrict__ G)
{
  const int proj = blockIdx.y >> 1;
  const int co0  = (blockIdx.y & 1) * 64;
  const float* __restrict__ W    = (proj==0) ? tw : ((proj==1) ? pw : gw);
  const float* __restrict__ bias = (proj==0) ? tb : ((proj==1) ? pb : gb);
  u16* __restrict__ out          = (proj==0) ? T  : ((proj==1) ? PHI : G);
  const int b   = blockIdx.z;
  const int hw0 = blockIdx.x * 64;
  const float* srcb = x + (size_t)b * 262144;   // 256*1024

  __shared__ float xs[16][64];
  __shared__ float wT[16][64];
  const int t = threadIdx.x;
  const int tc = t >> 4, th = t & 15;

  float acc[4][4];
  #pragma unroll
  for (int i=0;i<4;i++)
    #pragma unroll
    for (int j=0;j<4;j++) acc[i][j] = 0.f;

  for (int k0 = 0; k0 < 256; k0 += 16){
    __syncthreads();
    {
      int kk = t >> 4, col = (t & 15) * 4;
      *(float4*)&xs[kk][col] = *(const float4*)&srcb[(size_t)(k0+kk)*1024 + hw0 + col];
    }
    {
      int c = t >> 2, kk0 = (t & 3) * 4;
      float4 w4 = *(const float4*)&W[(size_t)(co0 + c) * 256 + k0 + kk0];
      wT[kk0+0][c] = w4.x; wT[kk0+1][c] = w4.y;
      wT[kk0+2][c] = w4.z; wT[kk0+3][c] = w4.w;
    }
    __syncthreads();
    #pragma unroll
    for (int kk=0;kk<16;kk++){
      float4 bv = *(const float4*)&xs[kk][th*4];
      float4 av = *(const float4*)&wT[kk][tc*4];
      float a[4]  = {av.x, av.y, av.z, av.w};
      float bb[4] = {bv.x, bv.y, bv.z, bv.w};
      #pragma unroll
      for (int i=0;i<4;i++)
        #pragma unroll
        for (int j=0;j<4;j++)
          acc[i][j] += a[i]*bb[j];
    }
  }
  #pragma unroll
  for (int i=0;i<4;i++){
    int co = co0 + tc*4 + i;
    float bs = bias[co];
    size_t base = ((size_t)b*128 + co)*1024 + hw0 + th*4;
    ushort4 u;
    u.x = f2bf(acc[i][0]+bs); u.y = f2bf(acc[i][1]+bs);
    u.z = f2bf(acc[i][2]+bs); u.w = f2bf(acc[i][3]+bs);
    *(ushort4*)&out[base] = u;
  }
}

// ---------------------------------------------------------------------------
// Kernel 2: bf16 2D transpose, dst[c][r] = src[r][c].  64x64 tiles.
// Used for:  phi [128][8192] -> K [8192][128]   (grid 128,2)
//            g   [8192][128] -> VT [128][8192]  (grid 2,128)
// ---------------------------------------------------------------------------
__global__ __launch_bounds__(256) void transpose_bf_kernel(
    const u16* __restrict__ src, u16* __restrict__ dst, int R, int C)
{
  __shared__ u16 tile[64][72];
  const int t = threadIdx.x;
  const int c0 = blockIdx.x*64, r0 = blockIdx.y*64;
  {
    int rr = t >> 2, cs = (t & 3) * 16;
    const u16* s = src + (size_t)(r0+rr)*C + c0 + cs;
    uint4 a0 = *(const uint4*)s;
    uint4 a1 = *(const uint4*)(s+8);
    *(uint4*)&tile[rr][cs]   = a0;
    *(uint4*)&tile[rr][cs+8] = a1;
  }
  __syncthreads();
  {
    int cc = t >> 2, rs = (t & 3) * 16;
    __align__(16) u16 tmp[16];
    #pragma unroll
    for (int i=0;i<16;i++) tmp[i] = tile[rs+i][cc];
    u16* d = dst + (size_t)(c0+cc)*R + r0 + rs;
    *(uint4*)d     = *(uint4*)&tmp[0];
    *(uint4*)(d+8) = *(uint4*)&tmp[8];
  }
}

// ---------------------------------------------------------------------------
// Kernel 3: flash attention, no-max-subtraction online softmax, key-split.
// Q=T [8192][128], K [8192][128], VT [128][8192], all bf16.
// blockIdx.x = query tile (32 q), blockIdx.y = key split s.
// Each block processes keys [s*tps*128, (s+1)*tps*128) and writes
// UNNORMALIZED partials: Opart[s][8192][128] fp32 and lpart[s][8192].
// 4 waves key-split each 128-key LDS tile; plain-sum merge (no max
// subtraction: |S| bounded ~43, exp safe in fp32).
// ---------------------------------------------------------------------------
__global__ __launch_bounds__(256) void attn_kernel(
    const u16* __restrict__ Tq, const u16* __restrict__ Kk,
    const u16* __restrict__ Vt, float* __restrict__ Opart,
    float* __restrict__ lpart, int tps)
{
  __shared__ __align__(16) char smem[47104];
  u16* Ks = (u16*)smem;                  // [128][136] bf16, +8 pad (bank/align)
  u16* Ps = (u16*)(smem + 34816);        // 4 x [32][48] bf16
  const int t = threadIdx.x;
  const int wave = t >> 6, lane = t & 63;
  const int quad = lane >> 4, n16 = lane & 15;
  const int q0 = blockIdx.x * 32;
  const int s  = blockIdx.y;
  u16* Pw = Ps + wave * 1536;
  const int kb = wave * 32;              // this wave's key slice in the tile

  float* Os = Opart + (size_t)s * 1048576;   // 8192*128
  float* ls = lpart + (size_t)s * 8192;

  // Q fragments: A[m=lane&15][k=quad*8+j]
  short8 qa[2][4];
  #pragma unroll
  for (int mt=0;mt<2;mt++)
    #pragma unroll
    for (int kc=0;kc<4;kc++)
      qa[mt][kc] = *(const short8*)(Tq + (size_t)(q0 + mt*16 + n16)*128 + kc*32 + quad*8);

  f32x4 o[2][8];
  float lp[2][4];
  #pragma unroll
  for (int mt=0;mt<2;mt++){
    #pragma unroll
    for (int dt=0;dt<8;dt++){ f32x4 z = {0.f,0.f,0.f,0.f}; o[mt][dt] = z; }
    #pragma unroll
    for (int r=0;r<4;r++) lp[mt][r] = 0.f;
  }

  const int kt_end = s*tps + tps;
  for (int kt=s*tps; kt<kt_end; kt++){
    const int key0 = kt*128;
    __syncthreads();
    // stage K tile [128 keys][128 d] -> LDS
    #pragma unroll
    for (int p=0;p<16;p++){
      int r = p*8 + (t>>5);
      int c = (t&31)*4;
      *(uint2*)(Ks + r*136 + c) = *(const uint2*)(Kk + (size_t)(key0 + r)*128 + c);
    }
    // V fragments straight from global VT (B[n=d][k=key]); issued early so
    // QK+softmax hides their latency.
    short8 vf[8];
    #pragma unroll
    for (int dt=0;dt<8;dt++)
      vf[dt] = *(const short8*)(Vt + (size_t)(dt*16 + n16)*8192 + key0 + kb + quad*8);
    __syncthreads();

    // K fragments: B[n=key][k=d]
    short8 kf[2][4];
    #pragma unroll
    for (int nt=0;nt<2;nt++)
      #pragma unroll
      for (int kc=0;kc<4;kc++)
        kf[nt][kc] = *(const short8*)(Ks + (kb + nt*16 + n16)*136 + kc*32 + quad*8);

    // S = Q K^T for this wave's 32x32 block
    f32x4 sacc[2][2];
    #pragma unroll
    for (int mt=0;mt<2;mt++)
      #pragma unroll
      for (int nt=0;nt<2;nt++){
        f32x4 a = {0.f,0.f,0.f,0.f};
        #pragma unroll
        for (int kc=0;kc<4;kc++)
          a = __builtin_amdgcn_mfma_f32_16x16x32_bf16(qa[mt][kc], kf[nt][kc], a, 0, 0, 0);
        sacc[mt][nt] = a;
      }

    // P = exp(S), l partials, C-layout -> LDS [q][key] for the PV A-operand.
    #pragma unroll
    for (int mt=0;mt<2;mt++)
      #pragma unroll
      for (int nt=0;nt<2;nt++)
        #pragma unroll
        for (int r=0;r<4;r++){
          float pe = exp2f(sacc[mt][nt][r] * 1.4426950408889634f);
          lp[mt][r] += pe;
          Pw[(mt*16 + quad*4 + r)*48 + nt*16 + n16] = f2bf(pe);
        }

    // P fragments: A[m=lane&15][k=quad*8+j]
    short8 pf[2];
    #pragma unroll
    for (int mt=0;mt<2;mt++)
      pf[mt] = *(const short8*)(Pw + (mt*16 + n16)*48 + quad*8);

    // O~ += P V
    #pragma unroll
    for (int dt=0;dt<8;dt++)
      #pragma unroll
      for (int mt=0;mt<2;mt++)
        o[mt][dt] = __builtin_amdgcn_mfma_f32_16x16x32_bf16(pf[mt], vf[dt], o[mt][dt], 0, 0, 0);
  }

  // row-sum l across the 16-lane column groups
  float l[2][4];
  #pragma unroll
  for (int mt=0;mt<2;mt++)
    #pragma unroll
    for (int r=0;r<4;r++){
      float v = lp[mt][r];
      v += __shfl_xor(v, 1, 64);
      v += __shfl_xor(v, 2, 64);
      v += __shfl_xor(v, 4, 64);
      v += __shfl_xor(v, 8, 64);
      l[mt][r] = v;
    }

  // cross-wave merge (plain sums; overlay Ks/Ps LDS). Om pitch 132 (pad: the
  // 4 quads of a wave write rows 4 apart -> pitch 128 would 4-way conflict).
  __syncthreads();
  float* Om = (float*)smem;             // [2][32][132] fp32 (33792 B)
  float* lm = (float*)(smem + 40960);   // 64 floats
  if (wave >= 2){
    const int w2 = wave - 2;
    #pragma unroll
    for (int mt=0;mt<2;mt++){
      #pragma unroll
      for (int dt=0;dt<8;dt++)
        #pragma unroll
        for (int r=0;r<4;r++)
          Om[(w2*32 + mt*16 + quad*4 + r)*132 + dt*16 + n16] = o[mt][dt][r];
      if (n16 == 0)
        #pragma unroll
        for (int r=0;r<4;r++) lm[w2*32 + mt*16 + quad*4 + r] = l[mt][r];
    }
  }
  __syncthreads();
  if (wave < 2){
    #pragma unroll
    for (int mt=0;mt<2;mt++){
      #pragma unroll
      for (int dt=0;dt<8;dt++)
        #pragma unroll
        for (int r=0;r<4;r++)
          o[mt][dt][r] += Om[(wave*32 + mt*16 + quad*4 + r)*132 + dt*16 + n16];
      #pragma unroll
      for (int r=0;r<4;r++) l[mt][r] += lm[wave*32 + mt*16 + quad*4 + r];
    }
  }
  __syncthreads();
  if (wave == 1){
    #pragma unroll
    for (int mt=0;mt<2;mt++){
      #pragma unroll
      for (int dt=0;dt<8;dt++)
        #pragma unroll
        for (int r=0;r<4;r++)
          Om[(mt*16 + quad*4 + r)*132 + dt*16 + n16] = o[mt][dt][r];
      if (n16 == 0)
        #pragma unroll
        for (int r=0;r<4;r++) lm[mt*16 + quad*4 + r] = l[mt][r];
    }
  }
  __syncthreads();
  if (wave == 0){
    #pragma unroll
    for (int mt=0;mt<2;mt++){
      #pragma unroll
      for (int dt=0;dt<8;dt++)
        #pragma unroll
        for (int r=0;r<4;r++)
          o[mt][dt][r] += Om[(mt*16 + quad*4 + r)*132 + dt*16 + n16];
      #pragma unroll
      for (int r=0;r<4;r++) l[mt][r] += lm[mt*16 + quad*4 + r];
    }
    // write UNNORMALIZED partial O~ and l for this split
    #pragma unroll
    for (int mt=0;mt<2;mt++){
      #pragma unroll
      for (int dt=0;dt<8;dt++)
        #pragma unroll
        for (int r=0;r<4;r++)
          Os[(size_t)(q0 + mt*16 + quad*4 + r)*128 + dt*16 + n16] = o[mt][dt][r];
      if (n16 == 0)
        #pragma unroll
        for (int r=0;r<4;r++) ls[q0 + mt*16 + quad*4 + r] = l[mt][r];
    }
  }
}

// ---------------------------------------------------------------------------
// Kernel 4: S-way partial merge + normalize + final 1x1 conv + bias + residual.
// out[b][co][hw] = sum_j Ww[co][j]*( sum_s Op[s]/sum_s l[s] )[b][j][hw]
//                  + Wb[co] + x[b][co][hw]
// grid: (16 hw-tiles, 4 co-tiles, 8 b)
// ---------------------------------------------------------------------------
__global__ __launch_bounds__(256) void final_kernel(
    const float* __restrict__ Ww, const float* __restrict__ Wb,
    const float* __restrict__ Opart, const float* __restrict__ lpart, int S,
    const float* __restrict__ x, float* __restrict__ outp)
{
  const int b   = blockIdx.z;
  const int co0 = blockIdx.y * 64;
  const int hw0 = blockIdx.x * 64;

  __shared__ float xs[16][64];
  __shared__ float wT[16][64];
  const int t = threadIdx.x;
  const int tc = t >> 4, th = t & 15;

  float acc[4][4];
  #pragma unroll
  for (int i=0;i<4;i++)
    #pragma unroll
    for (int j=0;j<4;j++) acc[i][j] = 0.f;

  for (int k0 = 0; k0 < 128; k0 += 16){
    __syncthreads();
    {
      int kk = t >> 4, col = (t & 15) * 4;
      size_t gflat = (size_t)b*131072 + (size_t)(k0+kk)*1024 + hw0 + col;
      int row = (int)(gflat >> 7);     // attention row of these 4 elements
      float4 a4; a4.x=0.f; a4.y=0.f; a4.z=0.f; a4.w=0.f;
      float lsum = 0.f;
      for (int sp=0; sp<S; sp++){
        float4 v = *(const float4*)&Opart[(size_t)sp*1048576 + gflat];
        a4.x += v.x; a4.y += v.y; a4.z += v.z; a4.w += v.w;
        lsum += lpart[sp*8192 + row];
      }
      float inv = 1.0f / lsum;
      a4.x *= inv; a4.y *= inv; a4.z *= inv; a4.w *= inv;
      *(float4*)&xs[kk][col] = a4;
    }
    {
      int c = t >> 2, kk0 = (t & 3) * 4;
      float4 w4 = *(const float4*)&Ww[(size_t)(co0 + c) * 128 + k0 + kk0];
      wT[kk0+0][c] = w4.x; wT[kk0+1][c] = w4.y;
      wT[kk0+2][c] = w4.z; wT[kk0+3][c] = w4.w;
    }
    __syncthreads();
    #pragma unroll
    for (int kk=0;kk<16;kk++){
      float4 bv = *(const float4*)&xs[kk][th*4];
      float4 av = *(const float4*)&wT[kk][tc*4];
      float a[4]  = {av.x, av.y, av.z, av.w};
      float bb[4] = {bv.x, bv.y, bv.z, bv.w};
      #pragma unroll
      for (int i=0;i<4;i++)
        #pragma unroll
        for (int j=0;j<4;j++)
          acc[i][j] += a[i]*bb[j];
    }
  }
  #pragma unroll
  for (int i=0;i<4;i++){
    int co = co0 + tc*4 + i;
    float bs = Wb[co];
    size_t base = ((size_t)b*256 + co)*1024 + hw0 + th*4;
    float4 xr = *(const float4*)&x[base];
    float4 r;
    r.x = acc[i][0] + bs + xr.x;
    r.y = acc[i][1] + bs + xr.y;
    r.z = acc[i][2] + bs + xr.z;
    r.w = acc[i][3] + bs + xr.w;
    *(float4*)&outp[base] = r;
  }
}

// ---------------------------------------------------------------------------
extern "C" void kernel_launch(void* const* d_in, const int* in_sizes, int n_in,
                              void* d_out, int out_size, void* d_ws, size_t ws_size,
                              hipStream_t stream)
{
  (void)in_sizes; (void)n_in; (void)out_size;
  const float* x  = (const float*)d_in[0];
  const float* tw = (const float*)d_in[1];
  const float* tb = (const float*)d_in[2];
  const float* pw = (const float*)d_in[3];
  const float* pb = (const float*)d_in[4];
  const float* gw = (const float*)d_in[5];
  const float* gb = (const float*)d_in[6];
  const float* Ww = (const float*)d_in[7];
  const float* Wb = (const float*)d_in[8];
  float* outp = (float*)d_out;

  char* ws = (char*)d_ws;
  const size_t MB = 1u << 20;
  u16*   Tbf   = (u16*)(ws);            // 2 MB  theta bf16 [8192][128]
  u16*   PHIbf = (u16*)(ws + 2*MB);     // 2 MB  phi   bf16 [128][8192] (natural flat)
  u16*   Gbf   = (u16*)(ws + 4*MB);     // 2 MB  g     bf16 [8192][128]
  u16*   Kbf   = (u16*)(ws + 6*MB);     // 2 MB  K = phi^T  [8192][128]
  u16*   VTbf  = (u16*)(ws + 8*MB);     // 2 MB  VT = g^T   [128][8192]

  // key-split factor chosen from available workspace (deterministic per call)
  int S = 1;
  if (ws_size >= 10*MB + 4*(4*MB + 32*1024)) S = 4;       // 26.13 MB
  else if (ws_size >= 10*MB + 2*(4*MB + 32*1024)) S = 2;  // 18.07 MB
  float* Opart = (float*)(ws + 10*MB);                    // S x 4 MB
  float* lpart = (float*)(ws + 10*MB + (size_t)S*4*MB);   // S x 32 KB

  proj3_kernel<<<dim3(16, 6, 8), 256, 0, stream>>>(x, tw, tb, pw, pb, gw, gb,
                                                   Tbf, PHIbf, Gbf);
  transpose_bf_kernel<<<dim3(128, 2), 256, 0, stream>>>(PHIbf, Kbf, 128, 8192);
  transpose_bf_kernel<<<dim3(2, 128), 256, 0, stream>>>(Gbf, VTbf, 8192, 128);
  attn_kernel<<<dim3(256, S), 256, 0, stream>>>(Tbf, Kbf, VTbf, Opart, lpart, 64/S);
  final_kernel<<<dim3(16, 4, 8), 256, 0, stream>>>(Ww, Wb, Opart, lpart, S, x, outp);
}